// Round 7
// baseline (297.710 us; speedup 1.0000x reference)
//
#include <hip/hip_runtime.h>

#define NN 20
#define BF_BASE 92448   // float index where bf16 transposed-weight region starts

typedef __attribute__((ext_vector_type(8))) short short8;
typedef __attribute__((ext_vector_type(4))) float floatx4;
typedef __attribute__((ext_vector_type(4))) unsigned int uintx4;

__device__ __forceinline__ float bf2f(unsigned short u){
  unsigned int x = ((unsigned int)u) << 16;
  return __builtin_bit_cast(float, x);
}
__device__ __forceinline__ unsigned short f2bf(float f){
  unsigned int x = __builtin_bit_cast(unsigned int, f);
  unsigned int r = x + 0x7fffu + ((x >> 16) & 1u);
  return (unsigned short)(r >> 16);
}
// round-half-up bf16 pair pack: 2 adds + 1 v_perm
__device__ __forceinline__ unsigned int pack2bf_rnd(float a, float b){
  unsigned int ua = __builtin_bit_cast(unsigned int, a) + 0x8000u;
  unsigned int ub = __builtin_bit_cast(unsigned int, b) + 0x8000u;
  return __builtin_amdgcn_perm(ub, ua, 0x07060302);  // ua.hi16 | ub.hi16<<16
}
__device__ __forceinline__ float lo_bf(unsigned int u){ return __builtin_bit_cast(float, u << 16); }
__device__ __forceinline__ float hi_bf(unsigned int u){ return __builtin_bit_cast(float, u & 0xffff0000u); }
__device__ __forceinline__ float fsilu(float x){ return x * (1.f/(1.f + __expf(-x))); }
__device__ __forceinline__ float ftanh(float x){ return 1.f - 2.f/(__expf(2.f*x) + 1.f); }

// ---------------- single fused prep kernel ----------------
// bf16 region layout (shorts, from BF_BASE):
//   W1Tn [3][128][64] @0      (BT[c][k]: c<64 -> W1[k][c] (t1), c>=64 -> W1[64+k][c-64] (t2))
//   W2T  [3][64][64]  @24576
//   CW1T [3][64][64]  @36864
//   NW1T [3][64][128] @49152
//   NW2T [3][64][64]  @73728
//   F1T  [64][64]     @86016  (F1T[n][k] = fc1_w[1+k][n])
struct PrepAll {
  const void* fsrc[19];
  const void* w1; const void* w2; const void* cw1;
  const void* nw1; const void* nw2; const void* fc1;
  const unsigned int* masks;
};

__global__ void prep_all(PrepAll a, float* __restrict__ ws){
  const int flag = (a.masks[0] == 0x3F800000u) ? 1 : 0;
  unsigned short* bf = (unsigned short*)(ws + BF_BASE);
  int ty = blockIdx.y;
  int idx = blockIdx.x * blockDim.x + threadIdx.x;

  if (ty < 19){
    static const int nn_[19]  = {512,64,24768,192,12288,192,192,3,24576,192,12288,192,12288,192,192,4160,64,64,1};
    static const int off_[19] = {0,512,576,25344,25536,37824,38016,38208,38224,62800,62992,75280,75472,87760,87952,88144,92304,92368,92432};
    if (idx < nn_[ty]){
      float v;
      if (flag) v = ((const float*)a.fsrc[ty])[idx];
      else      v = bf2f(((const unsigned short*)a.fsrc[ty])[idx]);
      ws[off_[ty] + idx] = v;
    }
    return;
  }
  auto ldbf = [&](const void* p, int i)->unsigned short {
    return flag ? f2bf(((const float*)p)[i]) : ((const unsigned short*)p)[i];
  };
  switch(ty){
    case 19: if (idx<24576){ int l=idx/8192, r=idx-l*8192, c=r>>6, k=r&63;
             int ksrc = (c<64)? k : 64+k; int nsrc = c&63;
             bf[idx] = ldbf(a.w1, l*8256 + ksrc*64 + nsrc); } break;
    case 20: if (idx<12288){ int l=idx>>12, r=idx&4095, n=r>>6, k=r&63;
             bf[24576+idx] = ldbf(a.w2, l*4096+k*64+n); } break;
    case 21: if (idx<12288){ int l=idx>>12, r=idx&4095, n=r>>6, k=r&63;
             bf[36864+idx] = ldbf(a.cw1, l*4096+k*64+n); } break;
    case 22: if (idx<24576){ int l=idx>>13, r=idx&8191, n=r>>7, k=r&127;
             bf[49152+idx] = ldbf(a.nw1, l*8192+k*64+n); } break;
    case 23: if (idx<12288){ int l=idx>>12, r=idx&4095, n=r>>6, k=r&63;
             bf[73728+idx] = ldbf(a.nw2, l*4096+k*64+n); } break;
    case 24: if (idx<4096){ int n=idx>>6, k=idx&63;
             bf[86016+idx] = ldbf(a.fc1, (k+1)*64+n); } break;
    default: break;
  }
}

// ---------------- fused EGNN main: one block per graph ----------------
// 256-thread (4-wave) blocks at launch_bounds(256,2): cap 256 total regs/wave
// (proven spill-free regime). LDS ~79.9KB -> 2 blocks/CU (8 waves/CU).
// One full-380-edge phase per layer (R6 structure, 5 barriers/layer), but
// edge tiles processed as 3 groups of ILP-2 (acc[4][2]+bm[2][2] ~ 56 live
// regs at the MFMA peak) -> kills R6's residual ~20KB/block spill stores.
__global__ __launch_bounds__(256, 2) void egnn_main(
    const void* __restrict__ obsv,
    const float* __restrict__ ws,
    const unsigned int* __restrict__ masks,
    const void* __restrict__ rnnv,
    void* __restrict__ outv)
{
  __shared__ float x_lds[NN][2];
  __shared__ float h_lds[NN][65];
  __shared__ float cw_lds[380][2];
  __shared__ __align__(16) unsigned short hbf[NN*72];
  __shared__ __align__(16) unsigned short mstore[380*72];
  __shared__ __align__(16) char uni[NN*132*4];   // t12f[20][132] fp32  ∪  n1bf (node phase)
  __shared__ __align__(16) unsigned short maggbf[NN*72];
  __shared__ float vals4[4][NN];
  __shared__ float vals[NN];

  float (*t12f)[132] = (float(*)[132])uni;            // edge-phase
  unsigned short* n1bf = (unsigned short*)uni;        // node-phase only (t12f dead)

  const int g = blockIdx.x;
  const int tid = threadIdx.x;
  const int flag = (masks[0] == 0x3F800000u) ? 1 : 0;
  const unsigned short* bf = (const unsigned short*)(ws + BF_BASE);

  // ---- rnn_states passthrough ----
  {
    int cnt = flag ? 16 : 8;
    if (tid < cnt){
      const uint4* s = (const uint4*)rnnv;
      uint4* d = (uint4*)((char*)outv + (flag ? 4096 : 2048));
      d[g*cnt + tid] = s[g*cnt + tid];
    }
  }

  // ---- load x (coords) ----
  if (tid < NN*2){
    int node = tid >> 1, c = tid & 1;
    float v;
    if (flag) v = ((const float*)obsv)[g*NN*10 + node*10 + c];
    else      v = bf2f(((const unsigned short*)obsv)[g*NN*10 + node*10 + c]);
    x_lds[node][c] = v;
  }

  // ---- embed (tiny, VALU; obs read directly from global) ----
  {
    const float* EW = ws;
    const float* EB = ws + 512;
    #pragma unroll 1
    for (int job = tid; job < 320; job += 256){
      int i = job >> 4, og = (job & 15) * 4;
      float a0=EB[og+0], a1=EB[og+1], a2=EB[og+2], a3=EB[og+3];
      #pragma unroll
      for (int k=0;k<8;k++){
        float v;
        if (flag) v = ((const float*)obsv)[g*NN*10 + i*10 + 2 + k];
        else      v = bf2f(((const unsigned short*)obsv)[g*NN*10 + i*10 + 2 + k]);
        const float* wr = EW + k*64 + og;
        a0 += v*wr[0]; a1 += v*wr[1]; a2 += v*wr[2]; a3 += v*wr[3];
      }
      h_lds[i][og+0]=a0; h_lds[i][og+1]=a1; h_lds[i][og+2]=a2; h_lds[i][og+3]=a3;
      *(uint2*)&hbf[i*72+og] = uint2{pack2bf_rnd(a0,a1), pack2bf_rnd(a2,a3)};
    }
  }
  __syncthreads();

  const int wvi = tid >> 6, ln = tid & 63;
  const int c15 = ln & 15, quad = ln >> 4;

  for (int l=0; l<3; l++){
    const float* W1  = ws + 576   + l*129*64;     // fp32; only row 128 used now
    const float* B1  = ws + 25344 + l*64;
    const float* B2  = ws + 37824 + l*64;
    const float* AW  = ws + 38016 + l*64;
    const float* ABp = ws + 38208 + l;
    const float* NB1 = ws + 62800 + l*64;
    const float* NB2 = ws + 75280 + l*64;
    const float* CB1 = ws + 87760 + l*64;
    const float* CW2 = ws + 87952 + l*64;
    const unsigned short* gW1Tn = bf + l*8192;
    const unsigned short* gW2T  = bf + 24576 + l*4096;
    const unsigned short* gCW1T = bf + 36864 + l*4096;
    const unsigned short* gNW1T = bf + 49152 + l*8192;
    const unsigned short* gNW2T = bf + 73728 + l*4096;
    const float* W1r = W1 + 8192;                 // radial weight row

    // ============== t-GEMM: t12 = h @ [W1top|W1bot] (+b1 on t1) ==============
    // M=20(pad32) x N=128 x K=64; 16 jobs (8 ct x 2 mt) over 4 waves
    #pragma unroll 1
    for (int job = wvi; job < 16; job += 4){
      int ct = job >> 1, mt = job & 1;
      int col = ct*16 + c15;
      float binit = (ct < 4) ? B1[col] : 0.f;
      floatx4 accm = floatx4{binit,binit,binit,binit};
      #pragma unroll
      for (int kc=0;kc<2;kc++){
        short8 bfr = *(const short8*)&gW1Tn[col*64 + kc*32 + quad*8];
        int m = mt*16 + c15;
        int node = m < NN ? m : NN-1;
        short8 afr = *(const short8*)&hbf[node*72 + kc*32 + quad*8];
        accm = __builtin_amdgcn_mfma_f32_16x16x32_bf16(afr, bfr, accm, 0,0,0);
      }
      #pragma unroll
      for (int reg=0;reg<4;reg++){
        int r = mt*16 + quad*4 + reg;
        if (r < NN) t12f[r][col] = accm[reg];
      }
    }
    __syncthreads();

    // =========================== EDGE PHASE (all 380 edges) ===========================
    // wave owns edges [wvi*96, wvi*96+95] = 6 tiles; 3 groups of 2 (ILP-2)
    #pragma unroll 1
    for (int grp=0; grp<3; grp++){
      int eA[2];
      float cn0[2], cn1[2];
      short8 bm[2][2];

      #pragma unroll
      for (int e2=0; e2<2; e2++){
        int et  = grp*2 + e2;
        int eT  = wvi*96 + et*16 + c15;     // edge this lane builds fragments for
        int ec  = eT < 380 ? eT : 379;
        eA[e2] = ec;
        int ei  = ec/19; int jj = ec - ei*19; int ej = jj + (jj >= ei ? 1 : 0);

        float cd0 = x_lds[ei][0] - x_lds[ej][0];
        float cd1 = x_lds[ei][1] - x_lds[ej][1];
        float radial = cd0*cd0 + cd1*cd1;
        float rinv = 1.f/(sqrtf(radial) + 1e-8f);
        cn0[e2] = cd0*rinv; cn1[e2] = cd1*rinv;

        // m1 B-fragments in-register: silu(t1[ei]+t2[ej]+radial*W1[128])
        const float* t1r = t12f[ei];
        const float* t2r = t12f[ej] + 64;
        #pragma unroll
        for (int kc=0;kc<2;kc++){
          int ch = kc*32 + quad*8;
          uintx4 u;
          #pragma unroll
          for (int hh=0; hh<2; hh++){
            floatx4 wa = *(const floatx4*)(W1r + ch + hh*4);
            floatx4 ta = *(const floatx4*)(t1r + ch + hh*4);
            floatx4 tb = *(const floatx4*)(t2r + ch + hh*4);
            float v0 = fsilu(ta[0]+tb[0]+radial*wa[0]);
            float v1 = fsilu(ta[1]+tb[1]+radial*wa[1]);
            float v2 = fsilu(ta[2]+tb[2]+radial*wa[2]);
            float v3 = fsilu(ta[3]+tb[3]+radial*wa[3]);
            if (hh==0){ u.x = pack2bf_rnd(v0,v1); u.y = pack2bf_rnd(v2,v3); }
            else      { u.z = pack2bf_rnd(v0,v1); u.w = pack2bf_rnd(v2,v3); }
          }
          bm[e2][kc] = __builtin_bit_cast(short8, u);
        }
      }

      // ---- GEMM2^T: m2^T = W2^T @ m1^T (2 tiles ILP), + attention gate ----
      floatx4 acc[4][2];
      #pragma unroll
      for (int ct=0;ct<4;ct++){
        floatx4 b4 = *(const floatx4*)(B2 + ct*16 + quad*4);
        acc[ct][0] = b4; acc[ct][1] = b4;
      }
      #pragma unroll
      for (int kc=0;kc<2;kc++)
        #pragma unroll
        for (int ct=0;ct<4;ct++){
          short8 afr = *(const short8*)&gW2T[(ct*16+c15)*64 + kc*32 + quad*8];
          #pragma unroll
          for (int e2=0;e2<2;e2++)
            acc[ct][e2] = __builtin_amdgcn_mfma_f32_16x16x32_bf16(afr, bm[e2][kc], acc[ct][e2], 0,0,0);
        }
      {
        floatx4 aw4[4];
        #pragma unroll
        for (int ct=0;ct<4;ct++) aw4[ct] = *(const floatx4*)(AW + ct*16 + quad*4);
        float ab = ABp[0];
        #pragma unroll
        for (int e2=0;e2<2;e2++){
          float pg = 0.f;
          #pragma unroll
          for (int ct=0;ct<4;ct++)
            #pragma unroll
            for (int r=0;r<4;r++){
              float v = fsilu(acc[ct][e2][r]);
              acc[ct][e2][r] = v;
              pg += v*aw4[ct][r];
            }
          pg += __shfl_xor(pg, 16);
          pg += __shfl_xor(pg, 32);
          float sg = 1.f/(1.f+__expf(-(pg + ab)));
          int eT = wvi*96 + (grp*2+e2)*16 + c15;
          if (eT < 380){
            int rowb = eT*72 + quad*4;
            #pragma unroll
            for (int ct=0;ct<4;ct++){
              *(uint2*)&mstore[rowb + ct*16] =
                uint2{pack2bf_rnd(acc[ct][e2][0]*sg, acc[ct][e2][1]*sg),
                      pack2bf_rnd(acc[ct][e2][2]*sg, acc[ct][e2][3]*sg)};
            }
          }
        }
      }

      // ---- GEMM3^T: CW1^T @ m^T, silu, dot CW2, tanh -> per-edge w ----
      {
        floatx4 acc3[4][2];
        #pragma unroll
        for (int ct=0;ct<4;ct++){
          floatx4 b4 = *(const floatx4*)(CB1 + ct*16 + quad*4);
          acc3[ct][0] = b4; acc3[ct][1] = b4;
        }
        #pragma unroll
        for (int kc=0;kc<2;kc++){
          short8 bfr[2];
          #pragma unroll
          for (int e2=0;e2<2;e2++)
            bfr[e2] = *(const short8*)&mstore[eA[e2]*72 + kc*32 + quad*8];  // wave-local rows
          #pragma unroll
          for (int ct=0;ct<4;ct++){
            short8 afr = *(const short8*)&gCW1T[(ct*16+c15)*64 + kc*32 + quad*8];
            #pragma unroll
            for (int e2=0;e2<2;e2++)
              acc3[ct][e2] = __builtin_amdgcn_mfma_f32_16x16x32_bf16(afr, bfr[e2], acc3[ct][e2], 0,0,0);
          }
        }
        floatx4 cw24[4];
        #pragma unroll
        for (int ct=0;ct<4;ct++) cw24[ct] = *(const floatx4*)(CW2 + ct*16 + quad*4);
        #pragma unroll
        for (int e2=0;e2<2;e2++){
          float pw = 0.f;
          #pragma unroll
          for (int ct=0;ct<4;ct++)
            #pragma unroll
            for (int r=0;r<4;r++) pw += fsilu(acc3[ct][e2][r])*cw24[ct][r];
          pw += __shfl_xor(pw, 16);
          pw += __shfl_xor(pw, 32);
          float wsel = ftanh(pw);
          int eT = wvi*96 + (grp*2+e2)*16 + c15;
          if (quad == 0 && eT < 380){
            cw_lds[eT][0] = cn0[e2]*wsel;
            cw_lds[eT][1] = cn1[e2]*wsel;
          }
        }
      }
    }
    __syncthreads();

    // ======================= AGGREGATION (all 20 nodes) =======================
    #pragma unroll 1
    for (int job = tid; job < 640; job += 256){
      int i = job >> 5, c2 = job & 31;       // node, uint column (2 ch)
      float s0=0.f, s1=0.f;
      int rb = i*19;
      const unsigned int* ms32 = (const unsigned int*)mstore;
      #pragma unroll
      for (int q=0;q<19;q++){
        unsigned int u = ms32[(rb+q)*36 + c2];
        s0 += lo_bf(u); s1 += hi_bf(u);
      }
      ((unsigned int*)maggbf)[i*36 + c2] = pack2bf_rnd(s0,s1);
    }
    if (tid < NN*2){
      int node = tid >> 1, c = tid & 1;
      float s = 0.f;
      int rb = node*19;
      #pragma unroll
      for (int q=0;q<19;q++) s += cw_lds[rb+q][c];
      x_lds[node][c] += s*(1.f/19.f);
    }
    __syncthreads();

    // =========================== NODE GEMM 1 ===========================
    #pragma unroll 1
    for (int job = wvi; job < 8; job += 4){
      int ct = job >> 1, mt = job & 1;
      int col = ct*16 + c15;
      float b = NB1[col];
      floatx4 accm = floatx4{b,b,b,b};
      #pragma unroll
      for (int kc=0;kc<4;kc++){
        short8 bfr = *(const short8*)&gNW1T[col*128 + kc*32 + quad*8];
        int m = mt*16 + c15;
        int node = m < NN ? m : NN-1;
        const unsigned short* abuf = (kc<2) ? &hbf[node*72 + kc*32 + quad*8]
                                            : &maggbf[node*72 + (kc-2)*32 + quad*8];
        short8 afr = *(const short8*)abuf;
        accm = __builtin_amdgcn_mfma_f32_16x16x32_bf16(afr, bfr, accm, 0,0,0);
      }
      #pragma unroll
      for (int reg=0;reg<4;reg++){
        int r = mt*16 + quad*4 + reg;
        if (r < NN) n1bf[r*72 + col] = f2bf(fsilu(accm[reg]));
      }
    }
    __syncthreads();

    // =========================== NODE GEMM 2 ===========================
    #pragma unroll 1
    for (int job = wvi; job < 8; job += 4){
      int ct = job >> 1, mt = job & 1;
      int col = ct*16 + c15;
      float b = NB2[col];
      floatx4 accm = floatx4{b,b,b,b};
      #pragma unroll
      for (int kc=0;kc<2;kc++){
        short8 bfr = *(const short8*)&gNW2T[col*64 + kc*32 + quad*8];
        int m = mt*16 + c15;
        int node = m < NN ? m : NN-1;
        short8 afr = *(const short8*)&n1bf[node*72 + kc*32 + quad*8];
        accm = __builtin_amdgcn_mfma_f32_16x16x32_bf16(afr, bfr, accm, 0,0,0);
      }
      #pragma unroll
      for (int reg=0;reg<4;reg++){
        int r = mt*16 + quad*4 + reg;
        if (r < NN){
          float hv = h_lds[r][col] + accm[reg];
          h_lds[r][col] = hv;
          hbf[r*72 + col] = f2bf(hv);
        }
      }
    }
    __syncthreads();
  }

  // =========================== HEAD ===========================
  {
    const float* F1 = ws + 88144;   // fp32 [65][64]; row 0 = xsq weights
    const float* F1B= ws + 92304;
    const float* F2 = ws + 92368;
    const float* F2B= ws + 92432;
    const unsigned short* gF1T = bf + 86016;

    #pragma unroll 1
    for (int job = wvi; job < 8; job += 4){
      int ct = job >> 1, mt = job & 1;
      int col = ct*16 + c15;
      float b = F1B[col];
      floatx4 accm = floatx4{b,b,b,b};
      #pragma unroll
      for (int kc=0;kc<2;kc++){
        short8 bfr = *(const short8*)&gF1T[col*64 + kc*32 + quad*8];
        int m = mt*16 + c15;
        int node = m < NN ? m : NN-1;
        short8 afr = *(const short8*)&hbf[node*72 + kc*32 + quad*8];
        accm = __builtin_amdgcn_mfma_f32_16x16x32_bf16(afr, bfr, accm, 0,0,0);
      }
      float f1r0 = F1[col];
      float f2v  = F2[col];
      #pragma unroll
      for (int reg=0;reg<4;reg++){
        int r = mt*16 + quad*4 + reg;
        int rr = r < NN ? r : NN-1;
        float x0 = x_lds[rr][0], x1 = x_lds[rr][1];
        float xsq = x0*x0 + x1*x1;
        float z = ftanh(accm[reg] + xsq*f1r0);
        float p = z*f2v;
        #pragma unroll
        for (int off=1; off<16; off<<=1) p += __shfl_xor(p, off, 16);
        if (c15 == 0 && r < NN) vals4[ct][r] = p;
      }
    }
    __syncthreads();
    if (tid < NN)
      vals[tid] = vals4[0][tid]+vals4[1][tid]+vals4[2][tid]+vals4[3][tid] + F2B[0];
    __syncthreads();
    if (tid == 0){
      float s = 0.f;
      #pragma unroll
      for (int i=0;i<NN;i++) s += vals[i];
      float v = s*(1.f/NN);
      if (flag) ((float*)outv)[g] = v;
      else      ((unsigned short*)outv)[g] = f2bf(v);
    }
  }
}

extern "C" void kernel_launch(void* const* d_in, const int* in_sizes, int n_in,
                              void* d_out, int out_size, void* d_ws, size_t ws_size,
                              hipStream_t stream) {
  static const int srcIdx[19] = {3,4,5,6,7,8,9,10,11,12,13,14,15,16,17,18,19,20,21};
  float* ws = (float*)d_ws;

  PrepAll pa;
  for (int i=0;i<19;i++) pa.fsrc[i] = d_in[srcIdx[i]];
  pa.w1  = d_in[5];  pa.w2  = d_in[7];  pa.cw1 = d_in[15];
  pa.nw1 = d_in[11]; pa.nw2 = d_in[13]; pa.fc1 = d_in[18];
  pa.masks = (const unsigned int*)d_in[2];

  prep_all<<<dim3(102,25), 256, 0, stream>>>(pa, ws);
  egnn_main<<<1024, 256, 0, stream>>>(d_in[0], ws,
                                      (const unsigned int*)d_in[2], d_in[1], d_out);
}

// Round 8
// 225.714 us; speedup vs baseline: 1.3190x; 1.3190x over previous
//
#include <hip/hip_runtime.h>

#define NN 20
#define BF_BASE 92448   // float index where bf16 transposed-weight region starts

typedef __attribute__((ext_vector_type(8))) short short8;
typedef __attribute__((ext_vector_type(4))) float floatx4;
typedef __attribute__((ext_vector_type(4))) unsigned int uintx4;

__device__ __forceinline__ float bf2f(unsigned short u){
  unsigned int x = ((unsigned int)u) << 16;
  return __builtin_bit_cast(float, x);
}
__device__ __forceinline__ unsigned short f2bf(float f){
  unsigned int x = __builtin_bit_cast(unsigned int, f);
  unsigned int r = x + 0x7fffu + ((x >> 16) & 1u);
  return (unsigned short)(r >> 16);
}
// round-half-up bf16 pair pack: 2 adds + 1 v_perm
__device__ __forceinline__ unsigned int pack2bf_rnd(float a, float b){
  unsigned int ua = __builtin_bit_cast(unsigned int, a) + 0x8000u;
  unsigned int ub = __builtin_bit_cast(unsigned int, b) + 0x8000u;
  return __builtin_amdgcn_perm(ub, ua, 0x07060302);  // ua.hi16 | ub.hi16<<16
}
__device__ __forceinline__ float lo_bf(unsigned int u){ return __builtin_bit_cast(float, u << 16); }
__device__ __forceinline__ float hi_bf(unsigned int u){ return __builtin_bit_cast(float, u & 0xffff0000u); }
// raw v_rcp_f32 (~1ulp) instead of IEEE div sequence (v_div_scale+fmas+fixup)
__device__ __forceinline__ float frcp(float x){ return __builtin_amdgcn_rcpf(x); }
__device__ __forceinline__ float fsilu(float x){ return x * frcp(1.f + __expf(-x)); }
__device__ __forceinline__ float ftanh(float x){ return 1.f - 2.f*frcp(__expf(2.f*x) + 1.f); }

// ---------------- single fused prep kernel ----------------
// bf16 region layout (shorts, from BF_BASE):
//   W1Tn [3][128][64] @0      (BT[c][k]: c<64 -> W1[k][c] (t1), c>=64 -> W1[64+k][c-64] (t2))
//   W2T  [3][64][64]  @24576
//   CW1T [3][64][64]  @36864
//   NW1T [3][64][128] @49152
//   NW2T [3][64][64]  @73728
//   F1T  [64][64]     @86016  (F1T[n][k] = fc1_w[1+k][n])
struct PrepAll {
  const void* fsrc[19];
  const void* w1; const void* w2; const void* cw1;
  const void* nw1; const void* nw2; const void* fc1;
  const unsigned int* masks;
};

__global__ void prep_all(PrepAll a, float* __restrict__ ws){
  const int flag = (a.masks[0] == 0x3F800000u) ? 1 : 0;
  unsigned short* bf = (unsigned short*)(ws + BF_BASE);
  int ty = blockIdx.y;
  int idx = blockIdx.x * blockDim.x + threadIdx.x;

  if (ty < 19){
    static const int nn_[19]  = {512,64,24768,192,12288,192,192,3,24576,192,12288,192,12288,192,192,4160,64,64,1};
    static const int off_[19] = {0,512,576,25344,25536,37824,38016,38208,38224,62800,62992,75280,75472,87760,87952,88144,92304,92368,92432};
    if (idx < nn_[ty]){
      float v;
      if (flag) v = ((const float*)a.fsrc[ty])[idx];
      else      v = bf2f(((const unsigned short*)a.fsrc[ty])[idx]);
      ws[off_[ty] + idx] = v;
    }
    return;
  }
  auto ldbf = [&](const void* p, int i)->unsigned short {
    return flag ? f2bf(((const float*)p)[i]) : ((const unsigned short*)p)[i];
  };
  switch(ty){
    case 19: if (idx<24576){ int l=idx/8192, r=idx-l*8192, c=r>>6, k=r&63;
             int ksrc = (c<64)? k : 64+k; int nsrc = c&63;
             bf[idx] = ldbf(a.w1, l*8256 + ksrc*64 + nsrc); } break;
    case 20: if (idx<12288){ int l=idx>>12, r=idx&4095, n=r>>6, k=r&63;
             bf[24576+idx] = ldbf(a.w2, l*4096+k*64+n); } break;
    case 21: if (idx<12288){ int l=idx>>12, r=idx&4095, n=r>>6, k=r&63;
             bf[36864+idx] = ldbf(a.cw1, l*4096+k*64+n); } break;
    case 22: if (idx<24576){ int l=idx>>13, r=idx&8191, n=r>>7, k=r&127;
             bf[49152+idx] = ldbf(a.nw1, l*8192+k*64+n); } break;
    case 23: if (idx<12288){ int l=idx>>12, r=idx&4095, n=r>>6, k=r&63;
             bf[73728+idx] = ldbf(a.nw2, l*4096+k*64+n); } break;
    case 24: if (idx<4096){ int n=idx>>6, k=idx&63;
             bf[86016+idx] = ldbf(a.fc1, (k+1)*64+n); } break;
    default: break;
  }
}

// ---------------- fused EGNN main: one block per graph ----------------
// 256-thread (4-wave) blocks at launch_bounds(256,2): cap 256 total regs/wave
// (proven spill-free regime). LDS ~79.9KB -> 2 blocks/CU (8 waves/CU).
// One full-380-edge phase per layer, edge tiles as 3 groups of ILP-2.
// This rev: raw v_rcp/v_sqrt for all activation divisions (was IEEE div
// sequence ~8-10 instrs each; ~50 divisions/lane/tile) -> VALU count cut.
__global__ __launch_bounds__(256, 2) void egnn_main(
    const void* __restrict__ obsv,
    const float* __restrict__ ws,
    const unsigned int* __restrict__ masks,
    const void* __restrict__ rnnv,
    void* __restrict__ outv)
{
  __shared__ float x_lds[NN][2];
  __shared__ float h_lds[NN][65];
  __shared__ float cw_lds[380][2];
  __shared__ __align__(16) unsigned short hbf[NN*72];
  __shared__ __align__(16) unsigned short mstore[380*72];
  __shared__ __align__(16) char uni[NN*132*4];   // t12f[20][132] fp32  ∪  n1bf (node phase)
  __shared__ __align__(16) unsigned short maggbf[NN*72];
  __shared__ float vals4[4][NN];
  __shared__ float vals[NN];

  float (*t12f)[132] = (float(*)[132])uni;            // edge-phase
  unsigned short* n1bf = (unsigned short*)uni;        // node-phase only (t12f dead)

  const int g = blockIdx.x;
  const int tid = threadIdx.x;
  const int flag = (masks[0] == 0x3F800000u) ? 1 : 0;
  const unsigned short* bf = (const unsigned short*)(ws + BF_BASE);

  // ---- rnn_states passthrough ----
  {
    int cnt = flag ? 16 : 8;
    if (tid < cnt){
      const uint4* s = (const uint4*)rnnv;
      uint4* d = (uint4*)((char*)outv + (flag ? 4096 : 2048));
      d[g*cnt + tid] = s[g*cnt + tid];
    }
  }

  // ---- load x (coords) ----
  if (tid < NN*2){
    int node = tid >> 1, c = tid & 1;
    float v;
    if (flag) v = ((const float*)obsv)[g*NN*10 + node*10 + c];
    else      v = bf2f(((const unsigned short*)obsv)[g*NN*10 + node*10 + c]);
    x_lds[node][c] = v;
  }

  // ---- embed (tiny, VALU; obs read directly from global) ----
  {
    const float* EW = ws;
    const float* EB = ws + 512;
    #pragma unroll 1
    for (int job = tid; job < 320; job += 256){
      int i = job >> 4, og = (job & 15) * 4;
      float a0=EB[og+0], a1=EB[og+1], a2=EB[og+2], a3=EB[og+3];
      #pragma unroll
      for (int k=0;k<8;k++){
        float v;
        if (flag) v = ((const float*)obsv)[g*NN*10 + i*10 + 2 + k];
        else      v = bf2f(((const unsigned short*)obsv)[g*NN*10 + i*10 + 2 + k]);
        const float* wr = EW + k*64 + og;
        a0 += v*wr[0]; a1 += v*wr[1]; a2 += v*wr[2]; a3 += v*wr[3];
      }
      h_lds[i][og+0]=a0; h_lds[i][og+1]=a1; h_lds[i][og+2]=a2; h_lds[i][og+3]=a3;
      *(uint2*)&hbf[i*72+og] = uint2{pack2bf_rnd(a0,a1), pack2bf_rnd(a2,a3)};
    }
  }
  __syncthreads();

  const int wvi = tid >> 6, ln = tid & 63;
  const int c15 = ln & 15, quad = ln >> 4;

  for (int l=0; l<3; l++){
    const float* W1  = ws + 576   + l*129*64;     // fp32; only row 128 used now
    const float* B1  = ws + 25344 + l*64;
    const float* B2  = ws + 37824 + l*64;
    const float* AW  = ws + 38016 + l*64;
    const float* ABp = ws + 38208 + l;
    const float* NB1 = ws + 62800 + l*64;
    const float* NB2 = ws + 75280 + l*64;
    const float* CB1 = ws + 87760 + l*64;
    const float* CW2 = ws + 87952 + l*64;
    const unsigned short* gW1Tn = bf + l*8192;
    const unsigned short* gW2T  = bf + 24576 + l*4096;
    const unsigned short* gCW1T = bf + 36864 + l*4096;
    const unsigned short* gNW1T = bf + 49152 + l*8192;
    const unsigned short* gNW2T = bf + 73728 + l*4096;
    const float* W1r = W1 + 8192;                 // radial weight row

    // ============== t-GEMM: t12 = h @ [W1top|W1bot] (+b1 on t1) ==============
    // M=20(pad32) x N=128 x K=64; 16 jobs (8 ct x 2 mt) over 4 waves
    #pragma unroll 1
    for (int job = wvi; job < 16; job += 4){
      int ct = job >> 1, mt = job & 1;
      int col = ct*16 + c15;
      float binit = (ct < 4) ? B1[col] : 0.f;
      floatx4 accm = floatx4{binit,binit,binit,binit};
      #pragma unroll
      for (int kc=0;kc<2;kc++){
        short8 bfr = *(const short8*)&gW1Tn[col*64 + kc*32 + quad*8];
        int m = mt*16 + c15;
        int node = m < NN ? m : NN-1;
        short8 afr = *(const short8*)&hbf[node*72 + kc*32 + quad*8];
        accm = __builtin_amdgcn_mfma_f32_16x16x32_bf16(afr, bfr, accm, 0,0,0);
      }
      #pragma unroll
      for (int reg=0;reg<4;reg++){
        int r = mt*16 + quad*4 + reg;
        if (r < NN) t12f[r][col] = accm[reg];
      }
    }
    __syncthreads();

    // =========================== EDGE PHASE (all 380 edges) ===========================
    // wave owns edges [wvi*96, wvi*96+95] = 6 tiles; 3 groups of 2 (ILP-2)
    #pragma unroll 1
    for (int grp=0; grp<3; grp++){
      int eA[2];
      float cn0[2], cn1[2];
      short8 bm[2][2];

      #pragma unroll
      for (int e2=0; e2<2; e2++){
        int et  = grp*2 + e2;
        int eT  = wvi*96 + et*16 + c15;     // edge this lane builds fragments for
        int ec  = eT < 380 ? eT : 379;
        eA[e2] = ec;
        int ei  = ec/19; int jj = ec - ei*19; int ej = jj + (jj >= ei ? 1 : 0);

        float cd0 = x_lds[ei][0] - x_lds[ej][0];
        float cd1 = x_lds[ei][1] - x_lds[ej][1];
        float radial = cd0*cd0 + cd1*cd1;
        float rinv = frcp(__builtin_amdgcn_sqrtf(radial) + 1e-8f);
        cn0[e2] = cd0*rinv; cn1[e2] = cd1*rinv;

        // m1 B-fragments in-register: silu(t1[ei]+t2[ej]+radial*W1[128])
        const float* t1r = t12f[ei];
        const float* t2r = t12f[ej] + 64;
        #pragma unroll
        for (int kc=0;kc<2;kc++){
          int ch = kc*32 + quad*8;
          uintx4 u;
          #pragma unroll
          for (int hh=0; hh<2; hh++){
            floatx4 wa = *(const floatx4*)(W1r + ch + hh*4);
            floatx4 ta = *(const floatx4*)(t1r + ch + hh*4);
            floatx4 tb = *(const floatx4*)(t2r + ch + hh*4);
            float v0 = fsilu(ta[0]+tb[0]+radial*wa[0]);
            float v1 = fsilu(ta[1]+tb[1]+radial*wa[1]);
            float v2 = fsilu(ta[2]+tb[2]+radial*wa[2]);
            float v3 = fsilu(ta[3]+tb[3]+radial*wa[3]);
            if (hh==0){ u.x = pack2bf_rnd(v0,v1); u.y = pack2bf_rnd(v2,v3); }
            else      { u.z = pack2bf_rnd(v0,v1); u.w = pack2bf_rnd(v2,v3); }
          }
          bm[e2][kc] = __builtin_bit_cast(short8, u);
        }
      }

      // ---- GEMM2^T: m2^T = W2^T @ m1^T (2 tiles ILP), + attention gate ----
      floatx4 acc[4][2];
      #pragma unroll
      for (int ct=0;ct<4;ct++){
        floatx4 b4 = *(const floatx4*)(B2 + ct*16 + quad*4);
        acc[ct][0] = b4; acc[ct][1] = b4;
      }
      #pragma unroll
      for (int kc=0;kc<2;kc++)
        #pragma unroll
        for (int ct=0;ct<4;ct++){
          short8 afr = *(const short8*)&gW2T[(ct*16+c15)*64 + kc*32 + quad*8];
          #pragma unroll
          for (int e2=0;e2<2;e2++)
            acc[ct][e2] = __builtin_amdgcn_mfma_f32_16x16x32_bf16(afr, bm[e2][kc], acc[ct][e2], 0,0,0);
        }
      {
        floatx4 aw4[4];
        #pragma unroll
        for (int ct=0;ct<4;ct++) aw4[ct] = *(const floatx4*)(AW + ct*16 + quad*4);
        float ab = ABp[0];
        #pragma unroll
        for (int e2=0;e2<2;e2++){
          float pg = 0.f;
          #pragma unroll
          for (int ct=0;ct<4;ct++)
            #pragma unroll
            for (int r=0;r<4;r++){
              float v = fsilu(acc[ct][e2][r]);
              acc[ct][e2][r] = v;
              pg += v*aw4[ct][r];
            }
          pg += __shfl_xor(pg, 16);
          pg += __shfl_xor(pg, 32);
          float sg = frcp(1.f+__expf(-(pg + ab)));
          int eT = wvi*96 + (grp*2+e2)*16 + c15;
          if (eT < 380){
            int rowb = eT*72 + quad*4;
            #pragma unroll
            for (int ct=0;ct<4;ct++){
              *(uint2*)&mstore[rowb + ct*16] =
                uint2{pack2bf_rnd(acc[ct][e2][0]*sg, acc[ct][e2][1]*sg),
                      pack2bf_rnd(acc[ct][e2][2]*sg, acc[ct][e2][3]*sg)};
            }
          }
        }
      }

      // ---- GEMM3^T: CW1^T @ m^T, silu, dot CW2, tanh -> per-edge w ----
      {
        floatx4 acc3[4][2];
        #pragma unroll
        for (int ct=0;ct<4;ct++){
          floatx4 b4 = *(const floatx4*)(CB1 + ct*16 + quad*4);
          acc3[ct][0] = b4; acc3[ct][1] = b4;
        }
        #pragma unroll
        for (int kc=0;kc<2;kc++){
          short8 bfr[2];
          #pragma unroll
          for (int e2=0;e2<2;e2++)
            bfr[e2] = *(const short8*)&mstore[eA[e2]*72 + kc*32 + quad*8];  // wave-local rows
          #pragma unroll
          for (int ct=0;ct<4;ct++){
            short8 afr = *(const short8*)&gCW1T[(ct*16+c15)*64 + kc*32 + quad*8];
            #pragma unroll
            for (int e2=0;e2<2;e2++)
              acc3[ct][e2] = __builtin_amdgcn_mfma_f32_16x16x32_bf16(afr, bfr[e2], acc3[ct][e2], 0,0,0);
          }
        }
        floatx4 cw24[4];
        #pragma unroll
        for (int ct=0;ct<4;ct++) cw24[ct] = *(const floatx4*)(CW2 + ct*16 + quad*4);
        #pragma unroll
        for (int e2=0;e2<2;e2++){
          float pw = 0.f;
          #pragma unroll
          for (int ct=0;ct<4;ct++)
            #pragma unroll
            for (int r=0;r<4;r++) pw += fsilu(acc3[ct][e2][r])*cw24[ct][r];
          pw += __shfl_xor(pw, 16);
          pw += __shfl_xor(pw, 32);
          float wsel = ftanh(pw);
          int eT = wvi*96 + (grp*2+e2)*16 + c15;
          if (quad == 0 && eT < 380){
            cw_lds[eT][0] = cn0[e2]*wsel;
            cw_lds[eT][1] = cn1[e2]*wsel;
          }
        }
      }
    }
    __syncthreads();

    // ======================= AGGREGATION (all 20 nodes) =======================
    #pragma unroll 1
    for (int job = tid; job < 640; job += 256){
      int i = job >> 5, c2 = job & 31;       // node, uint column (2 ch)
      float s0=0.f, s1=0.f;
      int rb = i*19;
      const unsigned int* ms32 = (const unsigned int*)mstore;
      #pragma unroll
      for (int q=0;q<19;q++){
        unsigned int u = ms32[(rb+q)*36 + c2];
        s0 += lo_bf(u); s1 += hi_bf(u);
      }
      ((unsigned int*)maggbf)[i*36 + c2] = pack2bf_rnd(s0,s1);
    }
    if (tid < NN*2){
      int node = tid >> 1, c = tid & 1;
      float s = 0.f;
      int rb = node*19;
      #pragma unroll
      for (int q=0;q<19;q++) s += cw_lds[rb+q][c];
      x_lds[node][c] += s*(1.f/19.f);
    }
    __syncthreads();

    // =========================== NODE GEMM 1 ===========================
    #pragma unroll 1
    for (int job = wvi; job < 8; job += 4){
      int ct = job >> 1, mt = job & 1;
      int col = ct*16 + c15;
      float b = NB1[col];
      floatx4 accm = floatx4{b,b,b,b};
      #pragma unroll
      for (int kc=0;kc<4;kc++){
        short8 bfr = *(const short8*)&gNW1T[col*128 + kc*32 + quad*8];
        int m = mt*16 + c15;
        int node = m < NN ? m : NN-1;
        const unsigned short* abuf = (kc<2) ? &hbf[node*72 + kc*32 + quad*8]
                                            : &maggbf[node*72 + (kc-2)*32 + quad*8];
        short8 afr = *(const short8*)abuf;
        accm = __builtin_amdgcn_mfma_f32_16x16x32_bf16(afr, bfr, accm, 0,0,0);
      }
      #pragma unroll
      for (int reg=0;reg<4;reg++){
        int r = mt*16 + quad*4 + reg;
        if (r < NN) n1bf[r*72 + col] = f2bf(fsilu(accm[reg]));
      }
    }
    __syncthreads();

    // =========================== NODE GEMM 2 ===========================
    #pragma unroll 1
    for (int job = wvi; job < 8; job += 4){
      int ct = job >> 1, mt = job & 1;
      int col = ct*16 + c15;
      float b = NB2[col];
      floatx4 accm = floatx4{b,b,b,b};
      #pragma unroll
      for (int kc=0;kc<2;kc++){
        short8 bfr = *(const short8*)&gNW2T[col*64 + kc*32 + quad*8];
        int m = mt*16 + c15;
        int node = m < NN ? m : NN-1;
        short8 afr = *(const short8*)&n1bf[node*72 + kc*32 + quad*8];
        accm = __builtin_amdgcn_mfma_f32_16x16x32_bf16(afr, bfr, accm, 0,0,0);
      }
      #pragma unroll
      for (int reg=0;reg<4;reg++){
        int r = mt*16 + quad*4 + reg;
        if (r < NN){
          float hv = h_lds[r][col] + accm[reg];
          h_lds[r][col] = hv;
          hbf[r*72 + col] = f2bf(hv);
        }
      }
    }
    __syncthreads();
  }

  // =========================== HEAD ===========================
  {
    const float* F1 = ws + 88144;   // fp32 [65][64]; row 0 = xsq weights
    const float* F1B= ws + 92304;
    const float* F2 = ws + 92368;
    const float* F2B= ws + 92432;
    const unsigned short* gF1T = bf + 86016;

    #pragma unroll 1
    for (int job = wvi; job < 8; job += 4){
      int ct = job >> 1, mt = job & 1;
      int col = ct*16 + c15;
      float b = F1B[col];
      floatx4 accm = floatx4{b,b,b,b};
      #pragma unroll
      for (int kc=0;kc<2;kc++){
        short8 bfr = *(const short8*)&gF1T[col*64 + kc*32 + quad*8];
        int m = mt*16 + c15;
        int node = m < NN ? m : NN-1;
        short8 afr = *(const short8*)&hbf[node*72 + kc*32 + quad*8];
        accm = __builtin_amdgcn_mfma_f32_16x16x32_bf16(afr, bfr, accm, 0,0,0);
      }
      float f1r0 = F1[col];
      float f2v  = F2[col];
      #pragma unroll
      for (int reg=0;reg<4;reg++){
        int r = mt*16 + quad*4 + reg;
        int rr = r < NN ? r : NN-1;
        float x0 = x_lds[rr][0], x1 = x_lds[rr][1];
        float xsq = x0*x0 + x1*x1;
        float z = ftanh(accm[reg] + xsq*f1r0);
        float p = z*f2v;
        #pragma unroll
        for (int off=1; off<16; off<<=1) p += __shfl_xor(p, off, 16);
        if (c15 == 0 && r < NN) vals4[ct][r] = p;
      }
    }
    __syncthreads();
    if (tid < NN)
      vals[tid] = vals4[0][tid]+vals4[1][tid]+vals4[2][tid]+vals4[3][tid] + F2B[0];
    __syncthreads();
    if (tid == 0){
      float s = 0.f;
      #pragma unroll
      for (int i=0;i<NN;i++) s += vals[i];
      float v = s*(1.f/NN);
      if (flag) ((float*)outv)[g] = v;
      else      ((unsigned short*)outv)[g] = f2bf(v);
    }
  }
}

extern "C" void kernel_launch(void* const* d_in, const int* in_sizes, int n_in,
                              void* d_out, int out_size, void* d_ws, size_t ws_size,
                              hipStream_t stream) {
  static const int srcIdx[19] = {3,4,5,6,7,8,9,10,11,12,13,14,15,16,17,18,19,20,21};
  float* ws = (float*)d_ws;

  PrepAll pa;
  for (int i=0;i<19;i++) pa.fsrc[i] = d_in[srcIdx[i]];
  pa.w1  = d_in[5];  pa.w2  = d_in[7];  pa.cw1 = d_in[15];
  pa.nw1 = d_in[11]; pa.nw2 = d_in[13]; pa.fc1 = d_in[18];
  pa.masks = (const unsigned int*)d_in[2];

  prep_all<<<dim3(102,25), 256, 0, stream>>>(pa, ws);
  egnn_main<<<1024, 256, 0, stream>>>(d_in[0], ws,
                                      (const unsigned int*)d_in[2], d_in[1], d_out);
}